// Round 1
// baseline (1353.451 us; speedup 1.0000x reference)
//
#include <hip/hip_runtime.h>

#define TEMP_ 0.2
#define NITER 10

// Assumes N = M = 8192 (multiples of 2048 cols / 64 rows / 8 rows), as the harness provides.

typedef _Float16 half_t;
struct __align__(16) H8 { half_t h[8]; };
typedef float floatx4 __attribute__((ext_vector_type(4)));

__device__ __forceinline__ float fast_rcp(float x){ return __builtin_amdgcn_rcpf(x); }

__device__ __forceinline__ float wsum(float v){
#pragma unroll
  for (int o = 32; o > 0; o >>= 1) v += __shfl_down(v, o, 64);
  return v;
}
__device__ __forceinline__ double wsumd(double v){
#pragma unroll
  for (int o = 32; o > 0; o >>= 1) v += __shfl_down(v, o, 64);
  return v;
}
__device__ __forceinline__ float wmin(float v){
#pragma unroll
  for (int o = 32; o > 0; o >>= 1) v = fminf(v, __shfl_down(v, o, 64));
  return v;
}

// order-preserving float<->uint map (works for negatives too)
__device__ __forceinline__ unsigned fenc(float f){
  unsigned u = __float_as_uint(f);
  return (u & 0x80000000u) ? ~u : (u | 0x80000000u);
}
__device__ __forceinline__ float fdec(unsigned u){
  return (u & 0x80000000u) ? __uint_as_float(u & 0x7FFFFFFFu) : __uint_as_float(~u);
}

__device__ __forceinline__ void get_stats(const double* __restrict__ sums,
                                          const unsigned* __restrict__ minbits,
                                          long long NM, float& cmin, float& kscale){
  double s  = sums[0];
  double ss = sums[1];
  double mean = s / (double)NM;
  double var  = (ss - mean * s) / (double)(NM - 1);   // ddof=1
  cmin  = fdec(*minbits);
  kscale = (float)(1.0 / (sqrt(var) * TEMP_));
}

// per-thread v for its own 32 columns: vr[j] = B_j * S * rcp(colsum_j)
// (finals call with S=1 since T needs v/S = B_j * rcp(colsum_j))
__device__ __forceinline__ void load_vr(const float* __restrict__ cs,
                                        const float* __restrict__ B,
                                        float S, int t, float* vr){
#pragma unroll
  for (int k = 0; k < 4; ++k){
    int c = k * 2048 + t * 8;
    float4 ca = *(const float4*)(cs + c);
    float4 cb = *(const float4*)(cs + c + 4);
    float4 ba = *(const float4*)(B + c);
    float4 bb = *(const float4*)(B + c + 4);
    vr[k*8+0] = ba.x * S * fast_rcp(ca.x);
    vr[k*8+1] = ba.y * S * fast_rcp(ca.y);
    vr[k*8+2] = ba.z * S * fast_rcp(ca.z);
    vr[k*8+3] = ba.w * S * fast_rcp(ca.w);
    vr[k*8+4] = bb.x * S * fast_rcp(cb.x);
    vr[k*8+5] = bb.y * S * fast_rcp(cb.y);
    vr[k*8+6] = bb.z * S * fast_rcp(cb.z);
    vr[k*8+7] = bb.w * S * fast_rcp(cb.w);
  }
}

// ---------------- init: zero scalars + both colsum buffers ----------------
__global__ void k_init(double* __restrict__ sums, double* __restrict__ Ssum,
                       unsigned* __restrict__ minbits,
                       float* __restrict__ c0, float* __restrict__ c1, int M){
  int i = blockIdx.x * blockDim.x + threadIdx.x;
  if (i == 0){ sums[0] = 0.0; sums[1] = 0.0; *Ssum = 0.0; *minbits = 0xFFFFFFFFu; }
  if (i < M){ c0[i] = 0.f; c1[i] = 0.f; }
}

// ---------------- pass 1: min / sum / sumsq over cdist ----------------
__global__ __launch_bounds__(256) void k_reduce(const float* __restrict__ cd, long long n4,
                                                double* __restrict__ sums,
                                                unsigned* __restrict__ minbits){
  const float4* c4 = (const float4*)cd;
  long long i0 = (long long)blockIdx.x * blockDim.x + threadIdx.x;
  long long stride = (long long)gridDim.x * blockDim.x;
  double s = 0.0, ss = 0.0;
  float  fs = 0.f, fss = 0.f;
  float  mn = __int_as_float(0x7F800000); // +inf
  int cnt = 0;
  for (long long i = i0; i < n4; i += stride){
    float4 v = c4[i];
    mn = fminf(mn, fminf(fminf(v.x, v.y), fminf(v.z, v.w)));
    fs  += (v.x + v.y) + (v.z + v.w);
    fss += v.x*v.x + v.y*v.y + v.z*v.z + v.w*v.w;
    if (++cnt == 8){ s += fs; ss += fss; fs = 0.f; fss = 0.f; cnt = 0; }
  }
  s += fs; ss += fss;
  s = wsumd(s); ss = wsumd(ss); mn = wmin(mn);
  __shared__ double lds[8];
  __shared__ float  ldm[4];
  int lane = threadIdx.x & 63, wid = threadIdx.x >> 6;
  if (lane == 0){ lds[wid] = s; lds[4 + wid] = ss; ldm[wid] = mn; }
  __syncthreads();
  if (threadIdx.x == 0){
    unsafeAtomicAdd(&sums[0], lds[0] + lds[1] + lds[2] + lds[3]);
    unsafeAtomicAdd(&sums[1], lds[4] + lds[5] + lds[6] + lds[7]);
    atomicMin(minbits, fenc(fminf(fminf(ldm[0], ldm[1]), fminf(ldm[2], ldm[3]))));
  }
}

// ---------------- pass 2: E=exp fp16 (H8 writes), colsum (u=1), S ----------------
__global__ __launch_bounds__(256) void k_expcol(const float* __restrict__ cd, half_t* __restrict__ E,
                                                const double* __restrict__ sums,
                                                const unsigned* __restrict__ minbits,
                                                float* __restrict__ colsum, double* __restrict__ Ssum,
                                                int N, int M){
  float cmin, kscale;
  get_stats(sums, minbits, (long long)N * M, cmin, kscale);
  int t = threadIdx.x;
  int c0 = blockIdx.x * 2048 + t * 8;
  int r0 = blockIdx.y * 64;
  float a0=0.f,a1=0.f,a2=0.f,a3=0.f,a4=0.f,a5=0.f,a6=0.f,a7=0.f;
#pragma unroll 4
  for (int r = 0; r < 64; ++r){
    long long idx = (long long)(r0 + r) * M + c0;
    float4 va = *(const float4*)(cd + idx);
    float4 vb = *(const float4*)(cd + idx + 4);
    float e0 = __expf((cmin - va.x) * kscale);
    float e1 = __expf((cmin - va.y) * kscale);
    float e2 = __expf((cmin - va.z) * kscale);
    float e3 = __expf((cmin - va.w) * kscale);
    float e4 = __expf((cmin - vb.x) * kscale);
    float e5 = __expf((cmin - vb.y) * kscale);
    float e6 = __expf((cmin - vb.z) * kscale);
    float e7 = __expf((cmin - vb.w) * kscale);
    H8 o;
    o.h[0]=(half_t)e0; o.h[1]=(half_t)e1; o.h[2]=(half_t)e2; o.h[3]=(half_t)e3;
    o.h[4]=(half_t)e4; o.h[5]=(half_t)e5; o.h[6]=(half_t)e6; o.h[7]=(half_t)e7;
    *(H8*)(E + idx) = o;
    a0+=e0; a1+=e1; a2+=e2; a3+=e3; a4+=e4; a5+=e5; a6+=e6; a7+=e7;
  }
  unsafeAtomicAdd(&colsum[c0+0], a0);
  unsafeAtomicAdd(&colsum[c0+1], a1);
  unsafeAtomicAdd(&colsum[c0+2], a2);
  unsafeAtomicAdd(&colsum[c0+3], a3);
  unsafeAtomicAdd(&colsum[c0+4], a4);
  unsafeAtomicAdd(&colsum[c0+5], a5);
  unsafeAtomicAdd(&colsum[c0+6], a6);
  unsafeAtomicAdd(&colsum[c0+7], a7);
  float tot = wsum(((a0+a1)+(a2+a3)) + ((a4+a5)+(a6+a7)));
  __shared__ float lt[4];
  int lane = t & 63, wid = t >> 6;
  if (lane == 0) lt[wid] = tot;
  __syncthreads();
  if (t == 0) unsafeAtomicAdd(Ssum, (double)((lt[0] + lt[1]) + (lt[2] + lt[3])));
}

// ---------------- row pass (fused): v from colsum, rowsum, u out ----------------
__global__ __launch_bounds__(256) void k_rp(const half_t* __restrict__ E,
                                            const float* __restrict__ cs,
                                            const float* __restrict__ B,
                                            const float* __restrict__ A,
                                            const double* __restrict__ Ssum,
                                            float* __restrict__ u, int M){
  int t = threadIdx.x;
  int r0 = blockIdx.x * 8;
  float S = (float)(*Ssum);
  float vr[32];
  load_vr(cs, B, S, t, vr);
  float acc[8];
  const half_t* Eb = E + (long long)r0 * M;
#pragma unroll
  for (int r = 0; r < 8; ++r){
    float p = 0.f;
#pragma unroll
    for (int k = 0; k < 4; ++k){
      H8 hh = *(const H8*)(Eb + (long long)r * M + k * 2048 + t * 8);
      p += (float)hh.h[0]*vr[k*8+0] + (float)hh.h[1]*vr[k*8+1]
         + (float)hh.h[2]*vr[k*8+2] + (float)hh.h[3]*vr[k*8+3]
         + (float)hh.h[4]*vr[k*8+4] + (float)hh.h[5]*vr[k*8+5]
         + (float)hh.h[6]*vr[k*8+6] + (float)hh.h[7]*vr[k*8+7];
    }
    acc[r] = p;
  }
  __shared__ float lds[4][8];
  int lane = t & 63, wid = t >> 6;
#pragma unroll
  for (int r = 0; r < 8; ++r){
    float p = wsum(acc[r]);
    if (lane == 0) lds[wid][r] = p;
  }
  __syncthreads();
  if (t < 8){
    float rs = (lds[0][t] + lds[1][t]) + (lds[2][t] + lds[3][t]);
    u[r0 + t] = A[r0 + t] * S * fast_rcp(rs);
  }
}

// ---------------- col pass (fused): u in, colsum_next out (atomic), zero old buf ----------------
__global__ __launch_bounds__(256) void k_cp(const half_t* __restrict__ E,
                                            const float* __restrict__ u,
                                            float* __restrict__ cs_next,
                                            float* __restrict__ cs_zero, int M){
  int t = threadIdx.x;
  int c0 = blockIdx.x * 2048 + t * 8;
  int r0 = blockIdx.y * 64;
  // distributed zeroing of the buffer the NEXT k_cp will accumulate into
  int bid = blockIdx.y * gridDim.x + blockIdx.x;
  int z = bid * 16 + t;
  if (t < 16 && z < M) cs_zero[z] = 0.f;
  __shared__ float ul[64];
  if (t < 64) ul[t] = u[r0 + t];
  __syncthreads();
  float a0=0.f,a1=0.f,a2=0.f,a3=0.f,a4=0.f,a5=0.f,a6=0.f,a7=0.f;
#pragma unroll 8
  for (int r = 0; r < 64; ++r){
    float ur = ul[r];
    H8 hh = *(const H8*)(E + (long long)(r0 + r) * M + c0);
    a0 += ur * (float)hh.h[0];
    a1 += ur * (float)hh.h[1];
    a2 += ur * (float)hh.h[2];
    a3 += ur * (float)hh.h[3];
    a4 += ur * (float)hh.h[4];
    a5 += ur * (float)hh.h[5];
    a6 += ur * (float)hh.h[6];
    a7 += ur * (float)hh.h[7];
  }
  unsafeAtomicAdd(&cs_next[c0+0], a0);
  unsafeAtomicAdd(&cs_next[c0+1], a1);
  unsafeAtomicAdd(&cs_next[c0+2], a2);
  unsafeAtomicAdd(&cs_next[c0+3], a3);
  unsafeAtomicAdd(&cs_next[c0+4], a4);
  unsafeAtomicAdd(&cs_next[c0+5], a5);
  unsafeAtomicAdd(&cs_next[c0+6], a6);
  unsafeAtomicAdd(&cs_next[c0+7], a7);
}

// ---------------- final (E-sourced): T = u_i * E_ij * (B_j/colsum_j), rows [r_base, r_base+grid*8) ----------------
// Safe vs E/T aliasing only when r_base*32KB >= (r_base+rows)*16KB, i.e. rows <= r_base.
__global__ __launch_bounds__(256) void k_final_E(const half_t* __restrict__ E,
                                                 const float* __restrict__ u,
                                                 const float* __restrict__ cs,
                                                 const float* __restrict__ B,
                                                 float* __restrict__ T, int r_base, int M){
  int t = threadIdx.x;
  int r0 = r_base + blockIdx.x * 8;
  float vr[32];
  load_vr(cs, B, 1.0f, t, vr);   // vr = v_j / S = B_j * rcp(colsum_j)
  for (int r = 0; r < 8; ++r){
    int row = r0 + r;
    float ur = u[row];
#pragma unroll
    for (int k = 0; k < 4; ++k){
      long long idx = (long long)row * M + k * 2048 + t * 8;
      H8 hh = *(const H8*)(E + idx);
      floatx4 oa, ob;
      oa.x = ur * vr[k*8+0] * (float)hh.h[0];
      oa.y = ur * vr[k*8+1] * (float)hh.h[1];
      oa.z = ur * vr[k*8+2] * (float)hh.h[2];
      oa.w = ur * vr[k*8+3] * (float)hh.h[3];
      ob.x = ur * vr[k*8+4] * (float)hh.h[4];
      ob.y = ur * vr[k*8+5] * (float)hh.h[5];
      ob.z = ur * vr[k*8+6] * (float)hh.h[6];
      ob.w = ur * vr[k*8+7] * (float)hh.h[7];
      __builtin_nontemporal_store(oa, (floatx4*)(T + idx));
      __builtin_nontemporal_store(ob, (floatx4*)(T + idx + 4));
    }
  }
}

// ---------------- final (cdist-sourced) for low rows where E would be clobbered ----------------
__global__ __launch_bounds__(256) void k_final_cd(const float* __restrict__ cd,
                                                  const float* __restrict__ u,
                                                  const float* __restrict__ cs,
                                                  const float* __restrict__ B,
                                                  const double* __restrict__ sums,
                                                  const unsigned* __restrict__ minbits,
                                                  float* __restrict__ T, int N, int M){
  float cmin, kscale;
  get_stats(sums, minbits, (long long)N * M, cmin, kscale);
  int t = threadIdx.x;
  int r0 = blockIdx.x * 8;
  float vr[32];
  load_vr(cs, B, 1.0f, t, vr);   // v_j / S
  for (int r = 0; r < 8; ++r){
    int row = r0 + r;
    float ur = u[row];
#pragma unroll
    for (int k = 0; k < 4; ++k){
      long long idx = (long long)row * M + k * 2048 + t * 8;
      float4 a = *(const float4*)(cd + idx);
      float4 b = *(const float4*)(cd + idx + 4);
      floatx4 oa, ob;
      oa.x = ur * vr[k*8+0] * __expf((cmin - a.x) * kscale);
      oa.y = ur * vr[k*8+1] * __expf((cmin - a.y) * kscale);
      oa.z = ur * vr[k*8+2] * __expf((cmin - a.z) * kscale);
      oa.w = ur * vr[k*8+3] * __expf((cmin - a.w) * kscale);
      ob.x = ur * vr[k*8+4] * __expf((cmin - b.x) * kscale);
      ob.y = ur * vr[k*8+5] * __expf((cmin - b.y) * kscale);
      ob.z = ur * vr[k*8+6] * __expf((cmin - b.z) * kscale);
      ob.w = ur * vr[k*8+7] * __expf((cmin - b.w) * kscale);
      __builtin_nontemporal_store(oa, (floatx4*)(T + idx));
      __builtin_nontemporal_store(ob, (floatx4*)(T + idx + 4));
    }
  }
}

extern "C" void kernel_launch(void* const* d_in, const int* in_sizes, int n_in,
                              void* d_out, int out_size, void* d_ws, size_t ws_size,
                              hipStream_t stream){
  const float* cd = (const float*)d_in[0];
  const float* A  = (const float*)d_in[1];
  const float* B  = (const float*)d_in[2];
  int N = in_sizes[1];
  int M = in_sizes[2];
  float*  T = (float*)d_out;
  half_t* E = (half_t*)d_out;   // first N*M*2 bytes of d_out used as fp16 scratch for E

  char* ws = (char*)d_ws;
  double*   sums    = (double*)ws;          // [0]=sum, [1]=sumsq
  double*   Ssum    = (double*)(ws + 16);
  unsigned* minbits = (unsigned*)(ws + 24);
  float*    c0      = (float*)(ws + 32);    // colsum double-buffer
  float*    c1      = c0 + M;
  float*    u       = c1 + M;

  long long n4 = (long long)N * M / 4;

  k_init<<<(M + 255) / 256, 256, 0, stream>>>(sums, Ssum, minbits, c0, c1, M);
  k_reduce<<<2048, 256, 0, stream>>>(cd, n4, sums, minbits);
  k_expcol<<<dim3(M / 2048, N / 64), 256, 0, stream>>>(cd, E, sums, minbits, c0, Ssum, N, M);

  for (int it = 0; it < NITER; ++it){
    float* cur = (it & 1) ? c1 : c0;   // colsum(it)
    float* nxt = (it & 1) ? c0 : c1;   // colsum(it+1), zeroed by cp(it-1) (or k_init for it=0)
    k_rp<<<N / 8, 256, 0, stream>>>(E, cur, B, A, Ssum, u, M);
    if (it + 1 < NITER)
      k_cp<<<dim3(M / 2048, N / 64), 256, 0, stream>>>(E, u, nxt, cur, M);
  }
  float* csl = ((NITER - 1) & 1) ? c1 : c0;  // colsum used by the last row pass

  // T rows [N/2,N): reads E bytes [N/2*2M .. N*2M) = [64,128MiB), writes [128,256MiB) -> disjoint
  k_final_E<<<(N / 2) / 8, 256, 0, stream>>>(E, u, csl, B, T, N / 2, M);
  // T rows [N/4,N/2): reads [32,64MiB), writes [64,128MiB) -> disjoint (previous kernel done)
  k_final_E<<<(N / 4) / 8, 256, 0, stream>>>(E, u, csl, B, T, N / 4, M);
  // T rows [0,N/4): recompute exp from cdist (writing here clobbers E, which is no longer needed)
  k_final_cd<<<(N / 4) / 8, 256, 0, stream>>>(cd, u, csl, B, sums, minbits, T, N, M);
}